// Round 1
// baseline (1200.051 us; speedup 1.0000x reference)
//
#include <hip/hip_runtime.h>
#include <hip/hip_bf16.h>

// Shapes (fixed): B=16, N=300, NG=150, D=1024, H=16, HD=64, P=64
// Pipeline:
//   G0: q   = roi @ Wq + bq                      (4800 x 1024 x 1024) -> (B,N,D)
//   G1: kT  = trunc @ Wk + bk, stored (B,H,NG,HD)(2400 x 1024 x 1024)
//   G2: V   = trunc @ Wout-permuted, (B,H,NG,HD) (2400 x 1024 x 1024)
//   K4: fused pos-proj + QK^T + log/mask/label + softmax -> attn (B,N,H,160) (160 = NG padded, pad=0)
//   G3: out = attn @ V + bout  (256 batched GEMMs 300 x 160 x 64)

constexpr int BM = 128, BN = 64, BK = 16;

template<int MODE>
__global__ __launch_bounds__(256, 2) void gemm_k(
    const float* __restrict__ A, const float* __restrict__ Bm,
    const float* __restrict__ bias, float* __restrict__ out,
    int M, int K)
{
  __shared__ float As[BK][BM + 4];   // [k][m], padded
  __shared__ float Bs[BK][BN];       // [k][n]
  const int tid = threadIdx.x;
  const int bm0 = blockIdx.x * BM;
  const int bn0 = blockIdx.y * BN;
  const int z   = blockIdx.z;        // batch index for MODE 3
  const int ty = tid >> 4, tx = tid & 15;

  // ---- A staging: 128x16 tile = 512 float4, 2 per thread ----
  const int row0 = tid >> 2;          // 0..63
  const int row1 = row0 + 64;         // 64..127
  const int kkc  = (tid & 3) << 2;    // 0,4,8,12
  long arow0, arow1;
  {
    int r0 = min(bm0 + row0, M - 1);
    int r1 = min(bm0 + row1, M - 1);
    if (MODE == 0) {
      arow0 = (long)r0 * 1024; arow1 = (long)r1 * 1024;
    } else if (MODE == 1 || MODE == 2) {
      int b0 = r0 / 150, m0 = r0 - b0 * 150;
      int b1 = r1 / 150, m1 = r1 - b1 * 150;
      arow0 = (long)(b0 * 300 + m0) * 1024;
      arow1 = (long)(b1 * 300 + m1) * 1024;
    } else { // MODE 3: A = attn (B,N,16,160); row r = n
      int b = z >> 4, h = z & 15;
      arow0 = (long)(b * 4800 + r0 * 16 + h) * 160;
      arow1 = (long)(b * 4800 + r1 * 16 + h) * 160;
    }
  }
  // ---- B staging: 16x64 tile = 256 float4, 1 per thread ----
  const int bkk = tid >> 4;           // 0..15
  const int bnn = (tid & 15) << 2;    // 0..60
  long bcol;
  if (MODE == 0 || MODE == 1) {
    bcol = bn0 + bnn;                 // W row-major (K=1024 x N=1024)
  } else if (MODE == 2) {
    int c = bn0 + bnn;                // Wout (H,D,HD): B[k][c] = Wout[c>>6][k][c&63]
    bcol = (long)(c >> 6) * 65536 + (c & 63);
  } else {
    bcol = (long)z * 9600 + bnn;      // V slab (150x64), over-read to 160 is A=0-masked
  }

  float acc[8][4];
  #pragma unroll
  for (int i = 0; i < 8; ++i)
    #pragma unroll
    for (int j = 0; j < 4; ++j) acc[i][j] = 0.f;

  for (int k0 = 0; k0 < K; k0 += BK) {
    float4 a0 = *(const float4*)(A + arow0 + k0 + kkc);
    float4 a1 = *(const float4*)(A + arow1 + k0 + kkc);
    long boff;
    if (MODE == 0 || MODE == 1) boff = (long)(k0 + bkk) * 1024 + bcol;
    else                        boff = bcol + (long)(k0 + bkk) * 64;
    float4 b4 = *(const float4*)(Bm + boff);

    __syncthreads();  // previous tile fully consumed
    As[kkc + 0][row0] = a0.x; As[kkc + 1][row0] = a0.y;
    As[kkc + 2][row0] = a0.z; As[kkc + 3][row0] = a0.w;
    As[kkc + 0][row1] = a1.x; As[kkc + 1][row1] = a1.y;
    As[kkc + 2][row1] = a1.z; As[kkc + 3][row1] = a1.w;
    *(float4*)&Bs[bkk][bnn] = b4;
    __syncthreads();

    #pragma unroll
    for (int kk = 0; kk < BK; ++kk) {
      float4 av0 = *(const float4*)&As[kk][ty * 8];
      float4 av1 = *(const float4*)&As[kk][ty * 8 + 4];
      float4 bv  = *(const float4*)&Bs[kk][tx * 4];
      float ar[8] = {av0.x, av0.y, av0.z, av0.w, av1.x, av1.y, av1.z, av1.w};
      float br[4] = {bv.x, bv.y, bv.z, bv.w};
      #pragma unroll
      for (int i = 0; i < 8; ++i)
        #pragma unroll
        for (int j = 0; j < 4; ++j)
          acc[i][j] += ar[i] * br[j];
    }
  }

  // ---- epilogue ----
  const int b3 = (MODE == 3) ? (z >> 4) : 0;
  const int h3 = (MODE == 3) ? (z & 15) : 0;
  const int c0 = bn0 + tx * 4;
  #pragma unroll
  for (int i = 0; i < 8; ++i) {
    int r = bm0 + ty * 8 + i;
    if (r < M) {
      float vx = acc[i][0], vy = acc[i][1], vz = acc[i][2], vw = acc[i][3];
      if (MODE == 0) {
        float4 bb = *(const float4*)(bias + c0);
        vx += bb.x; vy += bb.y; vz += bb.z; vw += bb.w;
        float4 v = {vx, vy, vz, vw};
        *(float4*)(out + (long)r * 1024 + c0) = v;
      } else if (MODE == 1 || MODE == 2) {
        if (MODE == 1) {
          float4 bb = *(const float4*)(bias + c0);
          vx += bb.x; vy += bb.y; vz += bb.z; vw += bb.w;
        }
        int bb_ = r / 150, m = r - bb_ * 150;
        int hh = c0 >> 6, o = c0 & 63;
        float4 v = {vx, vy, vz, vw};
        *(float4*)(out + ((long)((bb_ * 16 + hh) * 150 + m) << 6) + o) = v;
      } else {
        float4 bb = *(const float4*)(bias + h3 * 64 + c0);
        vx += bb.x; vy += bb.y; vz += bb.z; vw += bb.w;
        float4 v = {vx, vy, vz, vw};
        *(float4*)(out + (long)(b3 * 300 + r) * 1024 + h3 * 64 + c0) = v;
      }
    }
  }
}

// Fused: pos = relu(pos_emb @ Wp + bp); waff = qk*scale + log(max(pos,1e-6));
// masked = (adj>0 ? waff : -9e15) + label; attn = softmax_m(masked); pad m in [150,160) with 0.
__global__ __launch_bounds__(256) void k4_attn(
    const float* __restrict__ q,       // (B,N,1024)
    const float* __restrict__ kT,      // (B,16,150,64)
    const float* __restrict__ pos_emb, // (B,45000,64)
    const float* __restrict__ Wp,      // (64,16)
    const float* __restrict__ bp,      // (16)
    const int*   __restrict__ adj,     // (B,300,150)
    const float* __restrict__ lab,     // (B,300,150)
    float* __restrict__ attn)          // (B,300,16,160)
{
  __shared__ float wp_s[64 * 16];
  __shared__ float bp_s[16];
  __shared__ float s_s[16 * 152];
  const int t = threadIdx.x;
  const int bn = blockIdx.x;
  const int b = bn / 300;
  const int h = t & 15;               // this thread's head is fixed

  // stage Wp (1024 floats = 256 float4) + bp
  ((float4*)wp_s)[t] = ((const float4*)Wp)[t];
  if (t < 16) bp_s[t] = bp[t];

  // q row for (b,n,h) into registers (64 floats)
  const float* qrow = q + (long)bn * 1024 + h * 64;
  float4 qr[16];
  #pragma unroll
  for (int j = 0; j < 16; ++j) qr[j] = ((const float4*)qrow)[j];
  __syncthreads();

  const float* kb  = kT + ((long)b * 16 + h) * 150 * 64;
  const float* pb  = pos_emb + (long)bn * 150 * 64;
  const int*   ar_ = adj + (long)bn * 150;
  const float* lr_ = lab + (long)bn * 150;

  for (int p = t; p < 2400; p += 256) {
    const int m = p >> 4;             // p = m*16 + h, h = t&15 invariant
    const float4* kr = (const float4*)(kb + m * 64);
    const float4* pr = (const float4*)(pb + m * 64);
    float qk = 0.f, pw0 = 0.f, pw1 = 0.f, pw2 = 0.f, pw3 = 0.f;
    #pragma unroll
    for (int j = 0; j < 16; ++j) {
      float4 k4 = kr[j];
      float4 a4 = qr[j];
      qk += a4.x * k4.x + a4.y * k4.y + a4.z * k4.z + a4.w * k4.w;
      float4 p4 = pr[j];
      pw0 += p4.x * wp_s[(4 * j + 0) * 16 + h];
      pw1 += p4.y * wp_s[(4 * j + 1) * 16 + h];
      pw2 += p4.z * wp_s[(4 * j + 2) * 16 + h];
      pw3 += p4.w * wp_s[(4 * j + 3) * 16 + h];
    }
    float pa = (pw0 + pw1) + (pw2 + pw3) + bp_s[h];
    float lg = __logf(fmaxf(pa, 1e-6f));
    float sc = qk * 0.125f + lg;                    // scale = 1/sqrt(64)
    float val = (ar_[m] > 0 ? sc : -9e15f) + lr_[m];
    s_s[h * 152 + m] = val;
  }
  __syncthreads();

  // softmax: group g = t>>4 owns row h=g, lanes l = t&15 split m
  const int g = t >> 4, l = t & 15;
  float mx = -3.4e38f;
  for (int m = l; m < 150; m += 16) mx = fmaxf(mx, s_s[g * 152 + m]);
  #pragma unroll
  for (int o = 8; o >= 1; o >>= 1) mx = fmaxf(mx, __shfl_xor(mx, o, 16));
  float sum = 0.f;
  for (int m = l; m < 150; m += 16) {
    float e = __expf(s_s[g * 152 + m] - mx);
    s_s[g * 152 + m] = e;
    sum += e;
  }
  #pragma unroll
  for (int o = 8; o >= 1; o >>= 1) sum += __shfl_xor(sum, o, 16);
  const float inv = 1.0f / sum;
  float* arow = attn + ((long)bn * 16 + g) * 160;
  for (int m = l; m < 160; m += 16)
    arow[m] = (m < 150) ? s_s[g * 152 + m] * inv : 0.f;
}

extern "C" void kernel_launch(void* const* d_in, const int* in_sizes, int n_in,
                              void* d_out, int out_size, void* d_ws, size_t ws_size,
                              hipStream_t stream) {
  const float* roi  = (const float*)d_in[0];
  const int*   adj  = (const int*)  d_in[1];
  const float* pos  = (const float*)d_in[2];
  const float* lab  = (const float*)d_in[3];
  const float* Wq   = (const float*)d_in[4];
  const float* bq   = (const float*)d_in[5];
  const float* Wk   = (const float*)d_in[6];
  const float* bk   = (const float*)d_in[7];
  const float* Wp   = (const float*)d_in[8];
  const float* bp   = (const float*)d_in[9];
  const float* Wout = (const float*)d_in[10];
  const float* bout = (const float*)d_in[11];
  float* out = (float*)d_out;
  float* ws  = (float*)d_ws;

  // ws layout (floats): q[4915200] | kT[2457600] | V[2457600 + 640 pad] | attn[12288000]
  float* q    = ws;
  float* kT   = ws + 4915200;
  float* V    = ws + 7372800;
  float* attn = ws + 9831040;

  gemm_k<0><<<dim3(38, 16, 1), 256, 0, stream>>>(roi,  Wq,   bq,      q,   4800, 1024);
  gemm_k<1><<<dim3(19, 16, 1), 256, 0, stream>>>(roi,  Wk,   bk,      kT,  2400, 1024);
  gemm_k<2><<<dim3(19, 16, 1), 256, 0, stream>>>(roi,  Wout, nullptr, V,   2400, 1024);
  k4_attn  <<<dim3(4800, 1, 1), 256, 0, stream>>>(q, kT, pos, Wp, bp, adj, lab, attn);
  gemm_k<3><<<dim3(3, 1, 256),  256, 0, stream>>>(attn, V,   bout,    out, 300,  160);
}

// Round 2
// 466.312 us; speedup vs baseline: 2.5735x; 2.5735x over previous
//
#include <hip/hip_runtime.h>

typedef unsigned int u32;
typedef unsigned short u16;
using bf16x8 = __attribute__((ext_vector_type(8))) short;
using f32x4  = __attribute__((ext_vector_type(4))) float;

// B=16, N=300, NG=150, D=1024, H=16, HD=64, P=64
// Pipeline (all bf16 MFMA except k_pos):
//  k_cvt_roi : roi fp32 -> bf16
//  k_prep_w  : Wq,Wk,Wout -> transposed bf16 [n][k]
//  k_gemm<0> : q16(B,H,300,64)  = roi @ Wq + bq
//  k_gemm<1> : kT16(B,H,150,64) = trunc @ Wk + bk ; VT16(B,H,64,160) = trunc @ Wout (transposed)
//  k_pos     : PWL(B,H,300,160) = adj>0 ? max(relu(pos@Wp+bp),1e-6)*exp(lab) : 0   (bf16)
//  k_attn    : attn(B,H,300,160) = softmax-equiv: pwl*exp(qk*scale - rowmax)/sum
//  k_out     : out(B,300,1024) = attn @ V + bout

__device__ __forceinline__ void gl_lds16(const void* g, void* l) {
  __builtin_amdgcn_global_load_lds((const __attribute__((address_space(1))) u32*)g,
                                   (__attribute__((address_space(3))) u32*)l, 16, 0, 0);
}
__device__ __forceinline__ u16 f2b(float f) {
  u32 x = __builtin_bit_cast(u32, f);
  u32 r = (x + 0x7FFFu + ((x >> 16) & 1u)) >> 16;
  return (u16)r;
}
__device__ __forceinline__ float b2f(u16 u) {
  u32 x = ((u32)u) << 16;
  return __builtin_bit_cast(float, x);
}
#define MFMA16(a,b,c) __builtin_amdgcn_mfma_f32_16x16x32_bf16((a),(b),(c),0,0,0)

// ---------------- prep: roi fp32 -> bf16 ----------------
__global__ __launch_bounds__(256) void k_cvt_roi(const float* __restrict__ in, u16* __restrict__ out) {
  int i = (blockIdx.x * 256 + threadIdx.x) * 8;  // total 4915200
  float4 a = *(const float4*)(in + i);
  float4 b = *(const float4*)(in + i + 4);
  int4 o;
  o.x = (int)((u32)f2b(a.x) | ((u32)f2b(a.y) << 16));
  o.y = (int)((u32)f2b(a.z) | ((u32)f2b(a.w) << 16));
  o.z = (int)((u32)f2b(b.x) | ((u32)f2b(b.y) << 16));
  o.w = (int)((u32)f2b(b.z) | ((u32)f2b(b.w) << 16));
  *(int4*)(out + i) = o;
}

// ---------------- prep: weight transpose fp32[k][n] -> bf16[n][k] ----------------
// MODE 0/1: plain 1024x1024. MODE 2: Wout(H,D,HD): B[k][c]=Wout[c>>6][k][c&63]
template<int MODE>
__global__ __launch_bounds__(256) void k_prep_w(const float* __restrict__ W, u16* __restrict__ out) {
  __shared__ float t[32][33];
  int kt = blockIdx.x * 32, nt = blockIdx.y * 32;
  int r = threadIdx.x >> 3, c4 = (threadIdx.x & 7) * 4;
  const float* src;
  if (MODE == 2) {
    int c = nt + c4; int h = c >> 6, o = c & 63;
    src = W + h * 65536 + (kt + r) * 64 + o;
  } else {
    src = W + (kt + r) * 1024 + nt + c4;
  }
  float4 v = *(const float4*)src;
  t[r][c4] = v.x; t[r][c4 + 1] = v.y; t[r][c4 + 2] = v.z; t[r][c4 + 3] = v.w;
  __syncthreads();
  ushort4 o4;
  o4.x = f2b(t[c4 + 0][r]); o4.y = f2b(t[c4 + 1][r]);
  o4.z = f2b(t[c4 + 2][r]); o4.w = f2b(t[c4 + 3][r]);
  *(ushort4*)(out + (nt + r) * 1024 + kt + c4) = o4;
}

// ---------------- MFMA GEMM: MODE 0 = q proj (M=4800,N=1024), MODE 1 = k/V (M=2400,N=2048) ----------------
template<int MODE>
__global__ __launch_bounds__(256) void k_gemm(
    const u16* __restrict__ A, const u16* __restrict__ Bt,
    const float* __restrict__ bias0, u16* __restrict__ out0, u16* __restrict__ out1)
{
  __shared__ char As[2][8192];
  __shared__ char Bs[2][8192];
  const int tid = threadIdx.x, lane = tid & 63, w = tid >> 6;
  const int M = MODE ? 2400 : 4800;
  const int bm0 = blockIdx.x * 128, bn0 = blockIdx.y * 128;

  long asrc[2], bsrc[2];
  #pragma unroll
  for (int c = 0; c < 2; ++c) {
    int row = w * 32 + c * 16 + (lane >> 2);
    int g = (lane & 3) ^ ((row >> 1) & 3);
    int rg = min(bm0 + row, M - 1);
    long grow;
    if (MODE == 0) grow = rg;
    else { int b = rg / 150; grow = b * 300 + (rg - b * 150); }
    asrc[c] = grow * 2048 + g * 16;
    bsrc[c] = (long)(bn0 + row) * 2048 + g * 16;
  }

  f32x4 acc[4][4];
  #pragma unroll
  for (int i = 0; i < 4; ++i)
    #pragma unroll
    for (int j = 0; j < 4; ++j) acc[i][j] = (f32x4){0.f, 0.f, 0.f, 0.f};
  const int wm = (w >> 1) * 64, wn = (w & 1) * 64;

  #pragma unroll
  for (int c = 0; c < 2; ++c) {
    gl_lds16((const char*)A + asrc[c], &As[0][w * 2048 + c * 1024]);
    gl_lds16((const char*)Bt + bsrc[c], &Bs[0][w * 2048 + c * 1024]);
  }
  asm volatile("s_waitcnt vmcnt(0)" ::: "memory");
  __syncthreads();

  for (int t = 0; t < 32; ++t) {
    int cur = t & 1;
    if (t < 31) {
      long ko = (long)(t + 1) * 64;
      #pragma unroll
      for (int c = 0; c < 2; ++c) {
        gl_lds16((const char*)A + asrc[c] + ko, &As[cur ^ 1][w * 2048 + c * 1024]);
        gl_lds16((const char*)Bt + bsrc[c] + ko, &Bs[cur ^ 1][w * 2048 + c * 1024]);
      }
    }
    bf16x8 af[4], bfr[4];
    #pragma unroll
    for (int mi = 0; mi < 4; ++mi) {
      int row = wm + mi * 16 + (lane & 15);
      af[mi] = *(const bf16x8*)&As[cur][row * 64 + (((lane >> 4)) ^ ((row >> 1) & 3)) * 16];
      int rowb = wn + mi * 16 + (lane & 15);
      bfr[mi] = *(const bf16x8*)&Bs[cur][rowb * 64 + (((lane >> 4)) ^ ((rowb >> 1) & 3)) * 16];
    }
    #pragma unroll
    for (int mi = 0; mi < 4; ++mi)
      #pragma unroll
      for (int ni = 0; ni < 4; ++ni)
        acc[mi][ni] = MFMA16(af[mi], bfr[ni], acc[mi][ni]);
    asm volatile("s_waitcnt vmcnt(0)" ::: "memory");
    __syncthreads();
  }

  #pragma unroll
  for (int mi = 0; mi < 4; ++mi) {
    #pragma unroll
    for (int rr = 0; rr < 4; ++rr) {
      int row = bm0 + wm + mi * 16 + (lane >> 4) * 4 + rr;
      if (row < M) {
        int b, nm;
        if (MODE == 0) { b = row / 300; nm = row - b * 300; }
        else           { b = row / 150; nm = row - b * 150; }
        #pragma unroll
        for (int ni = 0; ni < 4; ++ni) {
          int c = bn0 + wn + ni * 16 + (lane & 15);
          float v = acc[mi][ni][rr];
          if (MODE == 0) {
            v += bias0[c];
            out0[((long)(b * 16 + (c >> 6)) * 300 + nm) * 64 + (c & 63)] = f2b(v);
          } else {
            if (c < 1024) {
              v += bias0[c];
              out0[((long)(b * 16 + (c >> 6)) * 150 + nm) * 64 + (c & 63)] = f2b(v);
            } else {
              int c2 = c - 1024;
              out1[((long)(b * 16 + (c2 >> 6)) * 64 + (c2 & 63)) * 160 + nm] = f2b(v);
            }
          }
        }
      }
    }
  }
}

// ---------------- fused pos/mask/label -> PWL bf16 (B,H,300,160) ----------------
__global__ __launch_bounds__(256) void k_pos(
    const float* __restrict__ pos, const float* __restrict__ Wp, const float* __restrict__ bp,
    const int* __restrict__ adj, const float* __restrict__ lab, u16* __restrict__ PWL)
{
  __shared__ float wp[1024];
  __shared__ float bps[16];
  int t = threadIdx.x;
  ((float4*)wp)[t] = ((const float4*)Wp)[t];
  if (t < 16) bps[t] = bp[t];
  __syncthreads();
  long r0 = (long)blockIdx.x * 1024 + t;

  float accv[4][16];
  #pragma unroll
  for (int k = 0; k < 4; ++k)
    #pragma unroll
    for (int h = 0; h < 16; ++h) accv[k][h] = 0.f;

  #pragma unroll 4
  for (int j = 0; j < 16; ++j) {
    float pc[4][4];
    #pragma unroll
    for (int k = 0; k < 4; ++k) {
      long r = r0 + k * 256;
      float4 p = (r < 720000) ? ((const float4*)(pos + r * 64))[j] : make_float4(0.f, 0.f, 0.f, 0.f);
      pc[k][0] = p.x; pc[k][1] = p.y; pc[k][2] = p.z; pc[k][3] = p.w;
    }
    #pragma unroll
    for (int i = 0; i < 4; ++i) {
      #pragma unroll
      for (int h = 0; h < 16; ++h) {
        float wv = wp[(4 * j + i) * 16 + h];
        accv[0][h] += pc[0][i] * wv;
        accv[1][h] += pc[1][i] * wv;
        accv[2][h] += pc[2][i] * wv;
        accv[3][h] += pc[3][i] * wv;
      }
    }
  }
  #pragma unroll
  for (int k = 0; k < 4; ++k) {
    long r = r0 + k * 256;
    if (r >= 720000) continue;
    int adjv = adj[r]; float labv = lab[r];
    int b = (int)(r / 45000); int rem = (int)(r - (long)b * 45000);
    int n = rem / 150; int m = rem - n * 150;
    float el = __expf(labv);
    long base = (long)b * 768000 + n * 160 + m;
    #pragma unroll
    for (int h = 0; h < 16; ++h) {
      float pw = fmaxf(accv[k][h] + bps[h], 1e-6f);
      PWL[base + h * 48000] = (adjv > 0) ? f2b(pw * el) : (u16)0;
    }
  }
}

// ---------------- QK^T (MFMA) + softmax-equivalent -> attn bf16 ----------------
__global__ __launch_bounds__(256) void k_attn(
    const u16* __restrict__ q16, const u16* __restrict__ kT16,
    const u16* __restrict__ PWL, u16* __restrict__ attn)
{
  __shared__ char qb[8192];
  __shared__ char kb[20480];
  const int t = threadIdx.x, lane = t & 63, w = t >> 6;
  const int tile = blockIdx.x, h = blockIdx.y, b = blockIdx.z;
  const long slabq = (long)(b * 16 + h) * 38400;  // bytes (300*64*2)
  const long slabk = (long)(b * 16 + h) * 19200;  // bytes (150*64*2)

  #pragma unroll
  for (int c = 0; c < 2; ++c) {
    int off = w * 2048 + c * 1024 + lane * 16;
    int row = off >> 7; int g = ((off >> 4) & 7) ^ ((row >> 1) & 7);
    int rc = min(tile * 64 + row, 299);
    gl_lds16((const char*)q16 + slabq + (long)rc * 128 + g * 16, &qb[w * 2048 + c * 1024]);
  }
  #pragma unroll
  for (int i = 0; i < 5; ++i) {
    int c = w + i * 4;
    int off = c * 1024 + lane * 16;
    int row = off >> 7; int g = ((off >> 4) & 7) ^ ((row >> 1) & 7);
    int rc = min(row, 149);
    gl_lds16((const char*)kT16 + slabk + (long)rc * 128 + g * 16, &kb[c * 1024]);
  }
  asm volatile("s_waitcnt vmcnt(0)" ::: "memory");
  __syncthreads();

  bf16x8 aq[2];
  {
    int row = w * 16 + (lane & 15);
    int f = (row >> 1) & 7;
    aq[0] = *(const bf16x8*)&qb[row * 128 + (((lane >> 4)) ^ f) * 16];
    aq[1] = *(const bf16x8*)&qb[row * 128 + ((4 + (lane >> 4)) ^ f) * 16];
  }
  f32x4 acc[10];
  #pragma unroll
  for (int fi = 0; fi < 10; ++fi) acc[fi] = (f32x4){0.f, 0.f, 0.f, 0.f};
  #pragma unroll
  for (int fi = 0; fi < 10; ++fi) {
    int m = fi * 16 + (lane & 15);
    int fm = (m >> 1) & 7;
    bf16x8 b0 = *(const bf16x8*)&kb[m * 128 + (((lane >> 4)) ^ fm) * 16];
    bf16x8 b1 = *(const bf16x8*)&kb[m * 128 + ((4 + (lane >> 4)) ^ fm) * 16];
    acc[fi] = MFMA16(aq[0], b0, acc[fi]);
    acc[fi] = MFMA16(aq[1], b1, acc[fi]);
  }

  const long base = (long)(b * 16 + h) * 48000;
  #pragma unroll
  for (int r = 0; r < 4; ++r) {
    int n = tile * 64 + w * 16 + (lane >> 4) * 4 + r;
    int nc = min(n, 299);
    float pw[10], tv[10];
    float mx = -3.0e38f;
    #pragma unroll
    for (int fi = 0; fi < 10; ++fi) {
      int m = fi * 16 + (lane & 15);
      int mc = min(m, 149);
      float p = b2f(PWL[base + (long)nc * 160 + mc]);
      bool val = (m < 150) && (p > 0.f);
      pw[fi] = val ? p : 0.f;
      tv[fi] = acc[fi][r] * 0.125f;
      mx = fmaxf(mx, val ? tv[fi] : -3.0e38f);
    }
    #pragma unroll
    for (int o = 8; o >= 1; o >>= 1) mx = fmaxf(mx, __shfl_xor(mx, o, 16));
    float s = 0.f; float wv[10];
    #pragma unroll
    for (int fi = 0; fi < 10; ++fi) {
      wv[fi] = (pw[fi] > 0.f) ? pw[fi] * __expf(tv[fi] - mx) : 0.f;
      s += wv[fi];
    }
    #pragma unroll
    for (int o = 8; o >= 1; o >>= 1) s += __shfl_xor(s, o, 16);
    float inv = 1.f / s;
    if (n < 300) {
      #pragma unroll
      for (int fi = 0; fi < 10; ++fi) {
        int m = fi * 16 + (lane & 15);
        attn[base + (long)n * 160 + m] = f2b(wv[fi] * inv);
      }
    }
  }
}

// ---------------- out = attn @ V + bout ----------------
__global__ __launch_bounds__(256) void k_out(
    const u16* __restrict__ attn, const u16* __restrict__ VT,
    const float* __restrict__ bout, float* __restrict__ out)
{
  __shared__ char Ab[2][19456];
  __shared__ char Vb[2][4096];
  const int t = threadIdx.x, lane = t & 63, w = t >> 6;
  const int h = blockIdx.x, b = blockIdx.y;
  const long slabA = (long)(b * 16 + h) * 96000;  // bytes
  const long slabV = (long)(b * 16 + h) * 20480;  // bytes

  f32x4 acc[5][4];
  #pragma unroll
  for (int i = 0; i < 5; ++i)
    #pragma unroll
    for (int j = 0; j < 4; ++j) acc[i][j] = (f32x4){0.f, 0.f, 0.f, 0.f};

  #define STAGE_G3(ks, buf)                                                              \
    {                                                                                    \
      _Pragma("unroll")                                                                  \
      for (int i_ = 0; i_ < 5; ++i_) {                                                   \
        int c_ = w + i_ * 4;                                                             \
        if (c_ < 19) {                                                                   \
          int off_ = c_ * 1024 + lane * 16;                                              \
          int row_ = off_ >> 6; int lo_ = (off_ >> 4) & 3;                               \
          int rc_ = min(row_, 299);                                                      \
          gl_lds16((const char*)attn + slabA + (long)rc_ * 320 + (ks) * 64 +             \
                       ((lo_ ^ ((rc_ >> 1) & 3)) * 16), &Ab[buf][c_ * 1024]);            \
        }                                                                                \
      }                                                                                  \
      {                                                                                  \
        int off_ = w * 1024 + lane * 16;                                                 \
        int row_ = off_ >> 6; int lo_ = (off_ >> 4) & 3;                                 \
        gl_lds16((const char*)VT + slabV + (long)row_ * 320 + (ks) * 64 +                \
                     ((lo_ ^ ((row_ >> 1) & 3)) * 16), &Vb[buf][w * 1024]);              \
      }                                                                                  \
    }

  STAGE_G3(0, 0);
  asm volatile("s_waitcnt vmcnt(0)" ::: "memory");
  __syncthreads();

  for (int ks = 0; ks < 5; ++ks) {
    int cur = ks & 1;
    if (ks < 4) STAGE_G3(ks + 1, cur ^ 1);
    bf16x8 bfr[4];
    #pragma unroll
    for (int ni = 0; ni < 4; ++ni) {
      int o = ni * 16 + (lane & 15);
      bfr[ni] = *(const bf16x8*)&Vb[cur][o * 64 + (((lane >> 4) ^ ((o >> 1) & 3)) * 16)];
    }
    #pragma unroll
    for (int i = 0; i < 5; ++i) {
      int mi = w * 5 + i;
      if (mi < 19) {
        int n = mi * 16 + (lane & 15);
        bf16x8 af = *(const bf16x8*)&Ab[cur][n * 64 + (((lane >> 4) ^ ((n >> 1) & 3)) * 16)];
        #pragma unroll
        for (int ni = 0; ni < 4; ++ni)
          acc[i][ni] = MFMA16(af, bfr[ni], acc[i][ni]);
      }
    }
    asm volatile("s_waitcnt vmcnt(0)" ::: "memory");
    __syncthreads();
  }

  #pragma unroll
  for (int i = 0; i < 5; ++i) {
    int mi = w * 5 + i;
    if (mi >= 19) continue;
    #pragma unroll
    for (int rr = 0; rr < 4; ++rr) {
      int n = mi * 16 + (lane >> 4) * 4 + rr;
      if (n < 300) {
        #pragma unroll
        for (int ni = 0; ni < 4; ++ni) {
          int o = ni * 16 + (lane & 15);
          out[((long)(b * 300 + n)) * 1024 + h * 64 + o] = acc[i][ni][rr] + bout[h * 64 + o];
        }
      }
    }
  }
}

extern "C" void kernel_launch(void* const* d_in, const int* in_sizes, int n_in,
                              void* d_out, int out_size, void* d_ws, size_t ws_size,
                              hipStream_t stream) {
  const float* roi  = (const float*)d_in[0];
  const int*   adj  = (const int*)  d_in[1];
  const float* pos  = (const float*)d_in[2];
  const float* lab  = (const float*)d_in[3];
  const float* Wq   = (const float*)d_in[4];
  const float* bq   = (const float*)d_in[5];
  const float* Wk   = (const float*)d_in[6];
  const float* bk   = (const float*)d_in[7];
  const float* Wp   = (const float*)d_in[8];
  const float* bp   = (const float*)d_in[9];
  const float* Wout = (const float*)d_in[10];
  const float* bout = (const float*)d_in[11];
  float* out = (float*)d_out;

  char* W = (char*)d_ws;
  u16* roi16 = (u16*)(W);               //  9,830,400 B
  u16* q16   = (u16*)(W + 9830400);     //  9,830,400 B (B,H,300,64)
  u16* kT16  = (u16*)(W + 19660800);    //  4,915,200 B (B,H,150,64)
  u16* VT16  = (u16*)(W + 24576000);    //  5,242,880 B (B,H,64,160)
  u16* WqT   = (u16*)(W + 29818880);    //  2,097,152 B
  u16* WB12  = (u16*)(W + 31916032);    //  4,194,304 B (2048 x 1024)
  u16* PWL   = (u16*)(W + 36110336);    // 24,576,000 B (B,H,300,160)
  u16* attn  = (u16*)(W + 60686336);    // 24,576,000 B (B,H,300,160)  end 85,262,336

  k_cvt_roi<<<2400, 256, 0, stream>>>(roi, roi16);
  k_prep_w<0><<<dim3(32, 32), 256, 0, stream>>>(Wq, WqT);
  k_prep_w<1><<<dim3(32, 32), 256, 0, stream>>>(Wk, WB12);
  k_prep_w<2><<<dim3(32, 32), 256, 0, stream>>>(Wout, WB12 + 1024 * 1024);
  k_gemm<0><<<dim3(38, 8),  256, 0, stream>>>(roi16, WqT,  bq, q16,  (u16*)nullptr);
  k_gemm<1><<<dim3(19, 16), 256, 0, stream>>>(roi16, WB12, bk, kT16, VT16);
  k_pos<<<704, 256, 0, stream>>>(pos, Wp, bp, adj, lab, PWL);
  k_attn<<<dim3(5, 16, 16), 256, 0, stream>>>(q16, kT16, PWL, attn);
  k_out<<<dim3(16, 16), 256, 0, stream>>>(attn, VT16, bout, out);
}